// Round 10
// baseline (122.572 us; speedup 1.0000x reference)
//
#include <hip/hip_runtime.h>
#include <hip/hip_bf16.h>

// Problem: B=2, S=2048, H=1024, HEADS=16, HEAD_DIM=64. Wire dtype fp32; output fp32.
// R21: attn re-granularized: 256-thread blocks (4 waves x 32 q = 128 q), full
// 2048-kv sweep, DMA-dbuf 1-barrier schedule (R16), ones-MFMA psum (R17),
// LDS dieted to 40960 B -> EXACTLY 4 blocks/CU (163840 = 160K). Same 16
// waves/CU as before but 4 independent barrier groups instead of 2 -> barrier
// drains covered by other blocks; kv-split merge epilogue deleted. All swizzle
// constants identical to the proven R16 forms. qkv/oproj/ln unchanged (R18
// forms); cvt keeps the 512-block grid (R20, +3.7us).
#define SEQ     2048
#define BATCH   2
#define HID     1024
#define NHEADS  16
#define HD      64
#define MTOT    4096            // BATCH*SEQ
#define LNEPS   1e-6f
#define L2E     1.4426950408889634f
#define SHIFT2  26.0f           // base-2 static softmax shift

typedef __bf16 bf16_t;
typedef bf16_t bf16x8 __attribute__((ext_vector_type(8)));   // 4 VGPRs = K=32 MFMA A/B frag
typedef bf16_t bf16x4 __attribute__((ext_vector_type(4)));   // 2 VGPRs = K=16 MFMA A/B frag
typedef short  short4v __attribute__((ext_vector_type(4)));
typedef float  floatx4 __attribute__((ext_vector_type(4)));  // MFMA C/D frag

__device__ __forceinline__ floatx4 mfma16(bf16x8 a, bf16x8 b, floatx4 c) {
    return __builtin_amdgcn_mfma_f32_16x16x32_bf16(a, b, c, 0, 0, 0);
}
// K=16 bf16 MFMA (v_mfma_f32_16x16x16_bf16, 2-reg operands)
__device__ __forceinline__ floatx4 mfma16k16(bf16x4 a, bf16x4 b, floatx4 c) {
    short4v as = __builtin_bit_cast(short4v, a);
    short4v bs = __builtin_bit_cast(short4v, b);
    return __builtin_amdgcn_mfma_f32_16x16x16bf16_1k(as, bs, c, 0, 0, 0);
}
__device__ __forceinline__ bf16x8 ldg8(const bf16_t* p) { return *(const bf16x8*)p; }

__device__ __forceinline__ void glds16(const bf16_t* src, char* dst) {
    __builtin_amdgcn_global_load_lds(
        (const __attribute__((address_space(1))) unsigned int*)src,
        (__attribute__((address_space(3))) unsigned int*)dst, 16, 0, 0);
}

// Stage one 128x32 bf16 tile into LDS via global_load_lds width 16.
__device__ __forceinline__ void stage128x32(const bf16_t* __restrict__ g, int row_stride,
                                            int k0, bf16_t* lds, int wave, int lane)
{
#pragma unroll
    for (int j = 0; j < 2; j++) {
        const int rbase = wave * 32 + j * 16;
        const bf16_t* src = g + (size_t)(rbase + (lane >> 2)) * row_stride + k0 + (lane & 3) * 8;
        bf16_t* dst = lds + rbase * 32;
        __builtin_amdgcn_global_load_lds(
            (const __attribute__((address_space(1))) unsigned int*)src,
            (__attribute__((address_space(3))) unsigned int*)dst, 16, 0, 0);
    }
}
// Stage one 64x32 bf16 tile (wave w covers rows [w*16, w*16+16)).
__device__ __forceinline__ void stage64x32(const bf16_t* __restrict__ g, int row_stride,
                                           int k0, bf16_t* lds, int wave, int lane)
{
    const int rbase = wave * 16;
    const bf16_t* src = g + (size_t)(rbase + (lane >> 2)) * row_stride + k0 + (lane & 3) * 8;
    bf16_t* dst = lds + rbase * 32;
    __builtin_amdgcn_global_load_lds(
        (const __attribute__((address_space(1))) unsigned int*)src,
        (__attribute__((address_space(3))) unsigned int*)dst, 16, 0, 0);
}

// ---------------------------------------------------------------------------
// Kernel 0: fp32 -> bf16 conversion for X, Wq, Wk, Wv, Wo.
// ---------------------------------------------------------------------------
__global__ __launch_bounds__(256) void cvt_kernel(
    const float* sX, const float* sWq, const float* sWk, const float* sWv, const float* sWo,
    bf16_t* dX, bf16_t* dWq, bf16_t* dWk, bf16_t* dWv, bf16_t* dWo)
{
    const int z = blockIdx.z;
    const float* src; bf16_t* dst; int n;
    switch (z) {
        case 0:  src = sX;  dst = dX;  n = MTOT * HID; break;
        case 1:  src = sWq; dst = dWq; n = HID * HID;  break;
        case 2:  src = sWk; dst = dWk; n = HID * HID;  break;
        case 3:  src = sWv; dst = dWv; n = HID * HID;  break;
        default: src = sWo; dst = dWo; n = HID * HID;  break;
    }
    const int n4 = n >> 2;
    const int stride = gridDim.x * blockDim.x;
    for (int i = blockIdx.x * blockDim.x + threadIdx.x; i < n4; i += stride) {
        const float4 v = ((const float4*)src)[i];
        bf16_t o[4] = {(bf16_t)v.x, (bf16_t)v.y, (bf16_t)v.z, (bf16_t)v.w};
        *(unsigned long long*)(dst + 4 * i) = *(unsigned long long*)o;
    }
}

// ---------------------------------------------------------------------------
// Kernel 1: QKV projection (NT GEMM, m97 staging, BK=32). R16 form (2-barrier).
// Q pre-scaled by 0.125. Q,K stored [bh][s][d]; V TRANSPOSED [bh][d][s].
// ---------------------------------------------------------------------------
__global__ __launch_bounds__(256) void qkv_kernel(
    const bf16_t* __restrict__ X,
    const bf16_t* __restrict__ Wq, const float* __restrict__ bq,
    const bf16_t* __restrict__ Wk, const float* __restrict__ bk,
    const bf16_t* __restrict__ Wv, const float* __restrict__ bv,
    bf16_t* __restrict__ Qo, bf16_t* __restrict__ Ko, bf16_t* __restrict__ Vo)
{
    const int z = blockIdx.z;
    const bf16_t* W    = (z == 0) ? Wq : (z == 1) ? Wk : Wv;
    const float*  bias = (z == 0) ? bq : (z == 1) ? bk : bv;
    bf16_t*       out  = (z == 0) ? Qo : (z == 1) ? Ko : Vo;

    const int tid  = threadIdx.x;
    const int lane = tid & 63;
    const int wave = tid >> 6;
    const int l16  = lane & 15;
    const int quad = lane >> 4;
    const int m_blk = blockIdx.y * 128;
    const int n_blk = blockIdx.x * 128;
    const int m_w = (wave >> 1) * 64;
    const int n_w = (wave & 1) * 64;

    // union: staging (2 x 8192 B) / epilogue transpose (4 x 4608 B)
    __shared__ __align__(16) char smem[18432];
    bf16_t* As = (bf16_t*)smem;
    bf16_t* Bs = (bf16_t*)(smem + 8192);

    floatx4 acc[4][4];
#pragma unroll
    for (int i = 0; i < 4; i++)
#pragma unroll
        for (int j = 0; j < 4; j++) acc[i][j] = (floatx4)0.0f;

    for (int k0 = 0; k0 < HID; k0 += 32) {
        __syncthreads();                                   // WAR on tiles
        stage128x32(X + (size_t)m_blk * HID, HID, k0, As, wave, lane);
        stage128x32(W + (size_t)n_blk * HID, HID, k0, Bs, wave, lane);
        __syncthreads();                                   // staging visible

        bf16x8 a[4], b[4];
#pragma unroll
        for (int i = 0; i < 4; i++) a[i] = *(const bf16x8*)&As[(m_w + i * 16 + l16) * 32 + quad * 8];
#pragma unroll
        for (int j = 0; j < 4; j++) b[j] = *(const bf16x8*)&Bs[(n_w + j * 16 + l16) * 32 + quad * 8];
#pragma unroll
        for (int i = 0; i < 4; i++)
#pragma unroll
            for (int j = 0; j < 4; j++) acc[i][j] = mfma16(a[i], b[j], acc[i][j]);
    }
    __syncthreads();                                       // smem reusable

    float bv_[4];
#pragma unroll
    for (int j = 0; j < 4; j++) bv_[j] = bias[n_blk + n_w + j * 16 + l16];

    bf16_t* Tw = (bf16_t*)(smem + wave * 4608);            // per-wave 32 x 72

    if (z != 2) {
        // Q/K [bh][s][d]: LDS transpose (rows=s) -> coalesced b128 stores.
        const float scale = (z == 0) ? 0.125f : 1.0f;
        const int hN = (n_blk + n_w) >> 6;
#pragma unroll
        for (int ih = 0; ih < 2; ih++) {
#pragma unroll
            for (int i2 = 0; i2 < 2; i2++) {
                const int i = ih * 2 + i2;
#pragma unroll
                for (int j = 0; j < 4; j++)
#pragma unroll
                    for (int r = 0; r < 4; r++)
                        Tw[(i2 * 16 + quad * 4 + r) * 72 + j * 16 + l16] =
                            (bf16_t)((acc[i][j][r] + bv_[j]) * scale);
            }
#pragma unroll
            for (int p = 0; p < 4; p++) {
                const int srow = p * 8 + (lane >> 3);
                const int col  = (lane & 7) * 8;
                bf16x8 v = *(const bf16x8*)&Tw[srow * 72 + col];
                const int m = m_blk + m_w + ih * 32 + srow;
                const int bb = m >> 11, s = m & (SEQ - 1);
                *(bf16x8*)&out[(((size_t)(bb * NHEADS + hN)) * SEQ + s) * HD + col] = v;
            }
        }
    } else {
        // V^T [bh][d][s]: LDS transpose (rows=d, cols=s) -> coalesced b128
        // stores along s. Two chunks of 32 d each.
        const int m0 = m_blk + m_w;                        // 64-aligned
        const int bb = m0 >> 11, s0 = m0 & (SEQ - 1);
#pragma unroll
        for (int jh = 0; jh < 2; jh++) {
#pragma unroll
            for (int j2 = 0; j2 < 2; j2++) {
                const int j = jh * 2 + j2;
#pragma unroll
                for (int i = 0; i < 4; i++) {
                    bf16x4 pk;
#pragma unroll
                    for (int r = 0; r < 4; r++) pk[r] = (bf16_t)(acc[i][j][r] + bv_[j]);
                    *(bf16x4*)&Tw[(j2 * 16 + l16) * 72 + i * 16 + quad * 4] = pk;
                }
            }
#pragma unroll
            for (int p = 0; p < 4; p++) {
                const int srow = p * 8 + (lane >> 3);      // d-local 0..31
                const int col  = (lane & 7) * 8;           // s-local
                bf16x8 v = *(const bf16x8*)&Tw[srow * 72 + col];
                const int n = n_blk + n_w + jh * 32 + srow;
                const int h = n >> 6, d = n & 63;
                *(bf16x8*)&out[(((size_t)(bb * NHEADS + h)) * HD + d) * SEQ + s0 + col] = v;
            }
        }
    }
}

// ---------------------------------------------------------------------------
// Kernel 2: flash attention. 256 threads / 4 waves, 32 q per wave (128 q per
// block), full 2048-kv sweep, double-buffered DMA staging with pre-swizzled
// sources (R16 constants), one barrier per kv tile. psum on the MFMA pipe
// (ones-A). LDS 40960 B -> exactly 4 blocks/CU.
// ---------------------------------------------------------------------------
__global__ __launch_bounds__(256, 4) void attn_kernel(
    const bf16_t* __restrict__ Q, const bf16_t* __restrict__ K,
    const bf16_t* __restrict__ Vt, const int* __restrict__ mask,
    bf16_t* __restrict__ ctx)
{
    const int B   = blockIdx.x;            // 0..511
    const int xcd = B & 7;
    const int idx = B >> 3;                // 0..63
    const int bh  = xcd * 4 + (idx & 3);   // 4 heads per XCD -> K/V L2-local
    const int q0  = (idx >> 2) * 128;      // block q base (0..1920)
    const int b   = bh >> 4;
    const int h   = bh & 15;
    const int tid  = threadIdx.x;          // 0..255
    const int wave = tid >> 6;             // 0..3
    const int lane = tid & 63;
    const int l16  = lane & 15;
    const int quad = lane >> 4;
    const int r7   = l16 & 7;

    const bf16_t* Qh = Q  + (size_t)bh * SEQ * HD;
    const bf16_t* Kh = K  + (size_t)bh * SEQ * HD;
    const bf16_t* Vh = Vt + (size_t)bh * HD * SEQ;    // [d][s]
    const int*    mk = mask + b * SEQ;

    // Kb0 8K | Vb0 8K | Kb1 8K | Vb1 8K | bias 8K = 40960 B (4 blocks/CU).
    // Epilogue per-wave scratch (4 x 4608 = 18432) reuses [0, 32768).
    __shared__ __align__(16) char smem[40960];
    char*  Kb0   = smem;
    char*  Vb0   = smem + 8192;
    char*  Kb1   = smem + 16384;
    char*  Vb1   = smem + 24576;
    float* bias2 = (float*)(smem + 32768);            // [SEQ]

    const int qw = q0 + wave * 32;

    // ---- staging geometry (256 threads cover 32 rows x 8 chunks; each STAGE
    // does rows srow and srow+32 of both K and V = 4 glds16/thread) ----
    const int srow = tid >> 3;                        // 0..31
    const int cK   = tid & 7;                         // 16B chunk
    // K source pre-swizzled: chunk cK of dest row r holds global chunk cK^(r&7)
    const bf16_t* srcK = Kh + (size_t)srow * HD + ((cK ^ (srow & 7)) * 8);
    // V source pre-swizzled (even mask): granules {2cK,2cK+1}^(r&14), contiguous
    const bf16_t* srcV = Vh + (size_t)srow * SEQ + (((2 * cK) ^ (srow & 14)) * 4);
    const int dofs = wave * 1024;                     // per-wave uniform dest offset

    // ---- read geometry ----
    // aK: logical chunk (kc*4+quad) at row l16 -> phys chunk ^ (l16&7)
    const int kb0 = l16 * 128 + (((quad    ) ^ r7) << 4);
    const int kb1 = l16 * 128 + (((4 + quad) ^ r7) << 4);

    // prologue: stage tile 0, fill bias
    glds16(srcK,            Kb0 + dofs);
    glds16(srcK + 32 * HD,  Kb0 + dofs + 4096);
    glds16(srcV,            Vb0 + dofs);
    glds16(srcV + 32 * SEQ, Vb0 + dofs + 4096);
    for (int i = tid; i < SEQ; i += 256)
        bias2[i] = (mk[i] ? 0.0f : -1.0e30f) - SHIFT2;

    bf16x8 bQ[2][2];
#pragma unroll
    for (int qh = 0; qh < 2; qh++)
#pragma unroll
        for (int kc = 0; kc < 2; kc++)
            bQ[qh][kc] = ldg8(Qh + (size_t)(qw + qh * 16 + l16) * HD + kc * 32 + quad * 8);

    const bf16x4 onesA = {(bf16_t)1.0f, (bf16_t)1.0f, (bf16_t)1.0f, (bf16_t)1.0f};
    floatx4 O[2][4];
    floatx4 psA[2];
#pragma unroll
    for (int qh = 0; qh < 2; qh++) {
        psA[qh] = (floatx4)0.0f;
#pragma unroll
        for (int dt = 0; dt < 4; dt++) O[qh][dt] = (floatx4)0.0f;
    }

    __syncthreads();                       // tile 0 + bias visible

#define STAGE(kt, KB, VB)                                            \
    do {                                                             \
        const bf16_t* sk_ = srcK + (size_t)(kt) * HD;                \
        const bf16_t* sv_ = srcV + (kt);                             \
        glds16(sk_,            (KB) + dofs);                         \
        glds16(sk_ + 32 * HD,  (KB) + dofs + 4096);                  \
        glds16(sv_,            (VB) + dofs);                         \
        glds16(sv_ + 32 * SEQ, (VB) + dofs + 4096);                  \
    } while (0)

#define COMPUTE(kt, KB, VB)                                                       \
    do {                                                                          \
        __builtin_amdgcn_s_setprio(1);                                            \
        _Pragma("unroll")                                                         \
        for (int kvt = 0; kvt < 4; kvt++) {                                       \
            bf16x8 aK0 = *(const bf16x8*)((KB) + kb0 + kvt * 2048);               \
            bf16x8 aK1 = *(const bf16x8*)((KB) + kb1 + kvt * 2048);               \
            const floatx4 ad = *(const floatx4*)&bias2[(kt) + kvt * 16 + quad * 4]; \
            bf16x4 pb[2];                                                         \
            _Pragma("unroll")                                                     \
            for (int qh = 0; qh < 2; qh++) {                                      \
                floatx4 s = (floatx4)0.0f;                                        \
                s = mfma16(aK0, bQ[qh][0], s);                                    \
                s = mfma16(aK1, bQ[qh][1], s);                                    \
                floatx4 p;                                                        \
                _Pragma("unroll")                                                 \
                for (int r = 0; r < 4; r++)                                       \
                    p[r] = __builtin_amdgcn_exp2f(fmaf(s[r], L2E, ad[r]));        \
                _Pragma("unroll")                                                 \
                for (int r = 0; r < 4; r++) pb[qh][r] = (bf16_t)p[r];             \
            }                                                                     \
            psA[0] = mfma16k16(onesA, pb[0], psA[0]);                             \
            psA[1] = mfma16k16(onesA, pb[1], psA[1]);                             \
            const int vofs = l16 * 128 + ((((kvt << 2) + quad) ^ (l16 & 14)) << 3); \
            _Pragma("unroll")                                                     \
            for (int dt = 0; dt < 4; dt++) {                                      \
                bf16x4 aV = *(const bf16x4*)((VB) + vofs + dt * 2048);            \
                O[0][dt] = mfma16k16(aV, pb[0], O[0][dt]);                        \
                O[1][dt] = mfma16k16(aV, pb[1], O[1][dt]);                        \
            }                                                                     \
        }                                                                         \
        __builtin_amdgcn_s_setprio(0);                                            \
    } while (0)

    for (int t = 0; t < 32; t += 2) {
        STAGE((t + 1) * 64, Kb1, Vb1);     // issue next-tile DMA (odd buf)
        COMPUTE(t * 64, Kb0, Vb0);
        __syncthreads();                   // drains vmcnt -> buf1 ready
        if (t + 2 < 32) STAGE((t + 2) * 64, Kb0, Vb0);
        COMPUTE((t + 1) * 64, Kb1, Vb1);
        __syncthreads();                   // buf0 ready
    }
#undef STAGE
#undef COMPUTE

#pragma unroll
    for (int qh = 0; qh < 2; qh++) {
        const float su = psA[qh][0];       // row-sum broadcast by ones-MFMA
        const float linv = (su > 0.0f) ? 1.0f / su : 0.0f;

        // per-wave scratch (loop's final barrier makes smem reusable)
        bf16_t* Pw = (bf16_t*)(smem + wave * 4608 + qh * 2304);  // 16x72
#pragma unroll
        for (int dt = 0; dt < 4; dt++) {
            floatx4 o = O[qh][dt] * linv;
            bf16x4 pk;
#pragma unroll
            for (int r = 0; r < 4; r++) pk[r] = (bf16_t)o[r];
            *(bf16x4*)&Pw[l16 * 72 + dt * 16 + quad * 4] = pk;
        }
#pragma unroll
        for (int ch = 0; ch < 2; ch++) {
            const int cc  = ch * 64 + lane;
            const int row = cc >> 3;
            const int col = (cc & 7) * 8;
            bf16x8 vv = *(const bf16x8*)&Pw[row * 72 + col];
            *(bf16x8*)&ctx[((size_t)(b * SEQ + qw + qh * 16 + row)) * HID + h * 64 + col] = vv;
        }
    }
}

// ---------------------------------------------------------------------------
// Kernel 3: res = ctx @ Wo^T + bo + X (residual fused). R16 form (2-barrier).
// 64x128 tile, 512 blocks.
// ---------------------------------------------------------------------------
__global__ __launch_bounds__(256) void oproj_kernel(
    const bf16_t* __restrict__ C, const bf16_t* __restrict__ Wo,
    const float* __restrict__ bo, const float* __restrict__ X,
    float* __restrict__ res)
{
    const int tid  = threadIdx.x;
    const int lane = tid & 63;
    const int wave = tid >> 6;
    const int l16  = lane & 15;
    const int quad = lane >> 4;
    const int m_blk = blockIdx.y * 64;
    const int n_blk = blockIdx.x * 128;
    const int n_w   = wave * 32;

    // union: staging (A 4096 + B 8192 B) / fp32 transpose (4 x 2304 B)
    __shared__ __align__(16) char smem[12288];
    bf16_t* As = (bf16_t*)smem;
    bf16_t* Bs = (bf16_t*)(smem + 4096);

    floatx4 acc[4][2];
#pragma unroll
    for (int i = 0; i < 4; i++)
#pragma unroll
        for (int j = 0; j < 2; j++) acc[i][j] = (floatx4)0.0f;

    for (int k0 = 0; k0 < HID; k0 += 32) {
        __syncthreads();
        stage64x32 (C  + (size_t)m_blk * HID, HID, k0, As, wave, lane);
        stage128x32(Wo + (size_t)n_blk * HID, HID, k0, Bs, wave, lane);
        __syncthreads();

        bf16x8 a[4], b[2];
#pragma unroll
        for (int i = 0; i < 4; i++) a[i] = *(const bf16x8*)&As[(i * 16 + l16) * 32 + quad * 8];
#pragma unroll
        for (int j = 0; j < 2; j++) b[j] = *(const bf16x8*)&Bs[(n_w + j * 16 + l16) * 32 + quad * 8];
#pragma unroll
        for (int i = 0; i < 4; i++)
#pragma unroll
            for (int j = 0; j < 2; j++) acc[i][j] = mfma16(a[i], b[j], acc[i][j]);
    }
    __syncthreads();                                       // smem reusable

    float bv_[2];
#pragma unroll
    for (int j = 0; j < 2; j++) bv_[j] = bo[n_blk + n_w + j * 16 + l16];

    float* Tw = (float*)(smem + wave * 2304);              // 16 x 36 fp32
#pragma unroll
    for (int ch = 0; ch < 4; ch++) {
#pragma unroll
        for (int j = 0; j < 2; j++)
#pragma unroll
            for (int r = 0; r < 4; r++)
                Tw[(quad * 4 + r) * 36 + j * 16 + l16] = acc[ch][j][r] + bv_[j];
#pragma unroll
        for (int cc = 0; cc < 2; cc++) {
            const int idx = cc * 64 + lane;                // 0..127
            const int row = idx >> 3;                      // 0..15
            const int col = (idx & 7) * 4;                 // 0..28
            float4 v = *(const float4*)&Tw[row * 36 + col];
            const int m = m_blk + ch * 16 + row;
            const float4 xv = *(const float4*)&X[(size_t)m * HID + n_blk + n_w + col];
            v.x += xv.x; v.y += xv.y; v.z += xv.z; v.w += xv.w;
            *(float4*)&res[(size_t)m * HID + n_blk + n_w + col] = v;
        }
    }
}

// ---------------------------------------------------------------------------
// Kernel 4: LayerNorm(resX) over rows of 1024 -> fp32 out (X already folded in)
// ---------------------------------------------------------------------------
__global__ __launch_bounds__(256) void ln_kernel(
    const float* __restrict__ res,
    const float* __restrict__ g, const float* __restrict__ be,
    float* __restrict__ out)
{
    __shared__ float red1[4], red2[4];
    const int row  = blockIdx.x;
    const int lane = threadIdx.x & 63;
    const int wave = threadIdx.x >> 6;
    const float4 v = ((const float4*)(res + (size_t)row * HID))[threadIdx.x];

    float s = v.x + v.y + v.z + v.w;
#pragma unroll
    for (int off = 1; off < 64; off <<= 1) s += __shfl_xor(s, off, 64);
    if (lane == 0) red1[wave] = s;
    __syncthreads();
    const float mu = (red1[0] + red1[1] + red1[2] + red1[3]) * (1.0f / HID);

    const float d0 = v.x - mu, d1 = v.y - mu, d2 = v.z - mu, d3 = v.w - mu;
    float ss = d0 * d0 + d1 * d1 + d2 * d2 + d3 * d3;
#pragma unroll
    for (int off = 1; off < 64; off <<= 1) ss += __shfl_xor(ss, off, 64);
    if (lane == 0) red2[wave] = ss;
    __syncthreads();
    const float var = (red2[0] + red2[1] + red2[2] + red2[3]) * (1.0f / HID);
    const float rstd = rsqrtf(var + LNEPS);

    const float4 gv = ((const float4*)g)[threadIdx.x];
    const float4 bv = ((const float4*)be)[threadIdx.x];
    float4 o;
    o.x = d0 * rstd * gv.x + bv.x;
    o.y = d1 * rstd * gv.y + bv.y;
    o.z = d2 * rstd * gv.z + bv.z;
    o.w = d3 * rstd * gv.w + bv.w;
    ((float4*)(out + (size_t)row * HID))[threadIdx.x] = o;
}

// ---------------------------------------------------------------------------
extern "C" void kernel_launch(void* const* d_in, const int* in_sizes, int n_in,
                              void* d_out, int out_size, void* d_ws, size_t ws_size,
                              hipStream_t stream)
{
    const float* X  = (const float*)d_in[0];
    const int* mask = (const int*)d_in[1];
    const float* Wq = (const float*)d_in[2];  const float* bq = (const float*)d_in[3];
    const float* Wk = (const float*)d_in[4];  const float* bk = (const float*)d_in[5];
    const float* Wv = (const float*)d_in[6];  const float* bv = (const float*)d_in[7];
    const float* Wo = (const float*)d_in[8];  const float* bo = (const float*)d_in[9];
    const float* g  = (const float*)d_in[10]; const float* be = (const float*)d_in[11];
    float* out = (float*)d_out;

    char* ws = (char*)d_ws;
    bf16_t* Qb  = (bf16_t*)(ws);                          // [0, 8M)
    bf16_t* Kb  = (bf16_t*)(ws + (8ull  << 20));          // [8M, 16M)
    bf16_t* Vb  = (bf16_t*)(ws + (16ull << 20));          // [16M, 24M)  V^T [bh][d][s]
    bf16_t* Cb  = (bf16_t*)(ws + (24ull << 20));          // [24M, 32M)
    float*  Rb  = (float*)(ws);                           // [0, 16M) aliases dead Q/K
    bf16_t* Xc  = (bf16_t*)(ws + (32ull << 20));          // [32M, 40M)
    bf16_t* Wqc = (bf16_t*)(ws + (40ull << 20));
    bf16_t* Wkc = (bf16_t*)(ws + (42ull << 20));
    bf16_t* Wvc = (bf16_t*)(ws + (44ull << 20));
    bf16_t* Woc = (bf16_t*)(ws + (46ull << 20));

    cvt_kernel <<<dim3(512, 1, 5), 256, 0, stream>>>(X, Wq, Wk, Wv, Wo, Xc, Wqc, Wkc, Wvc, Woc);
    qkv_kernel <<<dim3(8, 32, 3), 256, 0, stream>>>(Xc, Wqc, bq, Wkc, bk, Wvc, bv, Qb, Kb, Vb);
    attn_kernel<<<dim3(512), 256, 0, stream>>>(Qb, Kb, Vb, mask, Cb);
    oproj_kernel<<<dim3(8, 64), 256, 0, stream>>>(Cb, Woc, bo, X, Rb);
    ln_kernel  <<<MTOT, 256, 0, stream>>>(Rb, g, be, out);
}

// Round 11
// 120.963 us; speedup vs baseline: 1.0133x; 1.0133x over previous
//
#include <hip/hip_runtime.h>
#include <hip/hip_bf16.h>

// Problem: B=2, S=2048, H=1024, HEADS=16, HEAD_DIM=64. Wire dtype fp32; output fp32.
// R22: REVERT to R20 (session best, 121.3us). R21's 256-thread attn was
// grid-limited to 2 blocks/CU (512 blocks / 256 CUs) -- occupancy fell 33->18%
// and attn regressed 52.6->59.3. The 4-blocks/CU theory requires 1024 blocks,
// which forces either 16q/wave (loses R14's 2x fragment reuse) or global
// kv-split partials (R13's ~10us tax) -- both pre-falsified. R18's attn shape
// (512t, in-block kv-split, DMA-dbuf 1-barrier, ones-MFMA psum, setprio) is
// the verified local optimum at ~93% combined MFMA+VALU pipe pressure.
#define SEQ     2048
#define BATCH   2
#define HID     1024
#define NHEADS  16
#define HD      64
#define MTOT    4096            // BATCH*SEQ
#define KVHALF  1024            // per-half kv range
#define LNEPS   1e-6f
#define L2E     1.4426950408889634f
#define SHIFT2  26.0f           // base-2 static softmax shift

typedef __bf16 bf16_t;
typedef bf16_t bf16x8 __attribute__((ext_vector_type(8)));   // 4 VGPRs = K=32 MFMA A/B frag
typedef bf16_t bf16x4 __attribute__((ext_vector_type(4)));   // 2 VGPRs = K=16 MFMA A/B frag
typedef short  short4v __attribute__((ext_vector_type(4)));
typedef float  floatx4 __attribute__((ext_vector_type(4)));  // MFMA C/D frag

__device__ __forceinline__ floatx4 mfma16(bf16x8 a, bf16x8 b, floatx4 c) {
    return __builtin_amdgcn_mfma_f32_16x16x32_bf16(a, b, c, 0, 0, 0);
}
// K=16 bf16 MFMA (v_mfma_f32_16x16x16_bf16, 2-reg operands)
__device__ __forceinline__ floatx4 mfma16k16(bf16x4 a, bf16x4 b, floatx4 c) {
    short4v as = __builtin_bit_cast(short4v, a);
    short4v bs = __builtin_bit_cast(short4v, b);
    return __builtin_amdgcn_mfma_f32_16x16x16bf16_1k(as, bs, c, 0, 0, 0);
}
__device__ __forceinline__ bf16x8 ldg8(const bf16_t* p) { return *(const bf16x8*)p; }

__device__ __forceinline__ void glds16(const bf16_t* src, char* dst) {
    __builtin_amdgcn_global_load_lds(
        (const __attribute__((address_space(1))) unsigned int*)src,
        (__attribute__((address_space(3))) unsigned int*)dst, 16, 0, 0);
}

// Stage one 128x32 bf16 tile into LDS via global_load_lds width 16.
__device__ __forceinline__ void stage128x32(const bf16_t* __restrict__ g, int row_stride,
                                            int k0, bf16_t* lds, int wave, int lane)
{
#pragma unroll
    for (int j = 0; j < 2; j++) {
        const int rbase = wave * 32 + j * 16;
        const bf16_t* src = g + (size_t)(rbase + (lane >> 2)) * row_stride + k0 + (lane & 3) * 8;
        bf16_t* dst = lds + rbase * 32;
        __builtin_amdgcn_global_load_lds(
            (const __attribute__((address_space(1))) unsigned int*)src,
            (__attribute__((address_space(3))) unsigned int*)dst, 16, 0, 0);
    }
}
// Stage one 64x32 bf16 tile (wave w covers rows [w*16, w*16+16)).
__device__ __forceinline__ void stage64x32(const bf16_t* __restrict__ g, int row_stride,
                                           int k0, bf16_t* lds, int wave, int lane)
{
    const int rbase = wave * 16;
    const bf16_t* src = g + (size_t)(rbase + (lane >> 2)) * row_stride + k0 + (lane & 3) * 8;
    bf16_t* dst = lds + rbase * 32;
    __builtin_amdgcn_global_load_lds(
        (const __attribute__((address_space(1))) unsigned int*)src,
        (__attribute__((address_space(3))) unsigned int*)dst, 16, 0, 0);
}

// ---------------------------------------------------------------------------
// Kernel 0: fp32 -> bf16 conversion for X, Wq, Wk, Wv, Wo.
// ---------------------------------------------------------------------------
__global__ __launch_bounds__(256) void cvt_kernel(
    const float* sX, const float* sWq, const float* sWk, const float* sWv, const float* sWo,
    bf16_t* dX, bf16_t* dWq, bf16_t* dWk, bf16_t* dWv, bf16_t* dWo)
{
    const int z = blockIdx.z;
    const float* src; bf16_t* dst; int n;
    switch (z) {
        case 0:  src = sX;  dst = dX;  n = MTOT * HID; break;
        case 1:  src = sWq; dst = dWq; n = HID * HID;  break;
        case 2:  src = sWk; dst = dWk; n = HID * HID;  break;
        case 3:  src = sWv; dst = dWv; n = HID * HID;  break;
        default: src = sWo; dst = dWo; n = HID * HID;  break;
    }
    const int n4 = n >> 2;
    const int stride = gridDim.x * blockDim.x;
    for (int i = blockIdx.x * blockDim.x + threadIdx.x; i < n4; i += stride) {
        const float4 v = ((const float4*)src)[i];
        bf16_t o[4] = {(bf16_t)v.x, (bf16_t)v.y, (bf16_t)v.z, (bf16_t)v.w};
        *(unsigned long long*)(dst + 4 * i) = *(unsigned long long*)o;
    }
}

// ---------------------------------------------------------------------------
// Kernel 1: QKV projection (NT GEMM, m97 staging, BK=32). R16 form (2-barrier).
// Q pre-scaled by 0.125. Q,K stored [bh][s][d]; V TRANSPOSED [bh][d][s].
// ---------------------------------------------------------------------------
__global__ __launch_bounds__(256) void qkv_kernel(
    const bf16_t* __restrict__ X,
    const bf16_t* __restrict__ Wq, const float* __restrict__ bq,
    const bf16_t* __restrict__ Wk, const float* __restrict__ bk,
    const bf16_t* __restrict__ Wv, const float* __restrict__ bv,
    bf16_t* __restrict__ Qo, bf16_t* __restrict__ Ko, bf16_t* __restrict__ Vo)
{
    const int z = blockIdx.z;
    const bf16_t* W    = (z == 0) ? Wq : (z == 1) ? Wk : Wv;
    const float*  bias = (z == 0) ? bq : (z == 1) ? bk : bv;
    bf16_t*       out  = (z == 0) ? Qo : (z == 1) ? Ko : Vo;

    const int tid  = threadIdx.x;
    const int lane = tid & 63;
    const int wave = tid >> 6;
    const int l16  = lane & 15;
    const int quad = lane >> 4;
    const int m_blk = blockIdx.y * 128;
    const int n_blk = blockIdx.x * 128;
    const int m_w = (wave >> 1) * 64;
    const int n_w = (wave & 1) * 64;

    // union: staging (2 x 8192 B) / epilogue transpose (4 x 4608 B)
    __shared__ __align__(16) char smem[18432];
    bf16_t* As = (bf16_t*)smem;
    bf16_t* Bs = (bf16_t*)(smem + 8192);

    floatx4 acc[4][4];
#pragma unroll
    for (int i = 0; i < 4; i++)
#pragma unroll
        for (int j = 0; j < 4; j++) acc[i][j] = (floatx4)0.0f;

    for (int k0 = 0; k0 < HID; k0 += 32) {
        __syncthreads();                                   // WAR on tiles
        stage128x32(X + (size_t)m_blk * HID, HID, k0, As, wave, lane);
        stage128x32(W + (size_t)n_blk * HID, HID, k0, Bs, wave, lane);
        __syncthreads();                                   // staging visible

        bf16x8 a[4], b[4];
#pragma unroll
        for (int i = 0; i < 4; i++) a[i] = *(const bf16x8*)&As[(m_w + i * 16 + l16) * 32 + quad * 8];
#pragma unroll
        for (int j = 0; j < 4; j++) b[j] = *(const bf16x8*)&Bs[(n_w + j * 16 + l16) * 32 + quad * 8];
#pragma unroll
        for (int i = 0; i < 4; i++)
#pragma unroll
            for (int j = 0; j < 4; j++) acc[i][j] = mfma16(a[i], b[j], acc[i][j]);
    }
    __syncthreads();                                       // smem reusable

    float bv_[4];
#pragma unroll
    for (int j = 0; j < 4; j++) bv_[j] = bias[n_blk + n_w + j * 16 + l16];

    bf16_t* Tw = (bf16_t*)(smem + wave * 4608);            // per-wave 32 x 72

    if (z != 2) {
        // Q/K [bh][s][d]: LDS transpose (rows=s) -> coalesced b128 stores.
        const float scale = (z == 0) ? 0.125f : 1.0f;
        const int hN = (n_blk + n_w) >> 6;
#pragma unroll
        for (int ih = 0; ih < 2; ih++) {
#pragma unroll
            for (int i2 = 0; i2 < 2; i2++) {
                const int i = ih * 2 + i2;
#pragma unroll
                for (int j = 0; j < 4; j++)
#pragma unroll
                    for (int r = 0; r < 4; r++)
                        Tw[(i2 * 16 + quad * 4 + r) * 72 + j * 16 + l16] =
                            (bf16_t)((acc[i][j][r] + bv_[j]) * scale);
            }
#pragma unroll
            for (int p = 0; p < 4; p++) {
                const int srow = p * 8 + (lane >> 3);
                const int col  = (lane & 7) * 8;
                bf16x8 v = *(const bf16x8*)&Tw[srow * 72 + col];
                const int m = m_blk + m_w + ih * 32 + srow;
                const int bb = m >> 11, s = m & (SEQ - 1);
                *(bf16x8*)&out[(((size_t)(bb * NHEADS + hN)) * SEQ + s) * HD + col] = v;
            }
        }
    } else {
        // V^T [bh][d][s]: LDS transpose (rows=d, cols=s) -> coalesced b128
        // stores along s. Two chunks of 32 d each.
        const int m0 = m_blk + m_w;                        // 64-aligned
        const int bb = m0 >> 11, s0 = m0 & (SEQ - 1);
#pragma unroll
        for (int jh = 0; jh < 2; jh++) {
#pragma unroll
            for (int j2 = 0; j2 < 2; j2++) {
                const int j = jh * 2 + j2;
#pragma unroll
                for (int i = 0; i < 4; i++) {
                    bf16x4 pk;
#pragma unroll
                    for (int r = 0; r < 4; r++) pk[r] = (bf16_t)(acc[i][j][r] + bv_[j]);
                    *(bf16x4*)&Tw[(j2 * 16 + l16) * 72 + i * 16 + quad * 4] = pk;
                }
            }
#pragma unroll
            for (int p = 0; p < 4; p++) {
                const int srow = p * 8 + (lane >> 3);      // d-local 0..31
                const int col  = (lane & 7) * 8;           // s-local
                bf16x8 v = *(const bf16x8*)&Tw[srow * 72 + col];
                const int n = n_blk + n_w + jh * 32 + srow;
                const int h = n >> 6, d = n & 63;
                *(bf16x8*)&out[(((size_t)(bb * NHEADS + h)) * HD + d) * SEQ + s0 + col] = v;
            }
        }
    }
}

// ---------------------------------------------------------------------------
// Kernel 2: flash attention, in-block kv-split, double-buffered DMA staging.
// 512 threads / 8 waves: waves 0-3 kv[0,1024), waves 4-7 kv[1024,2048), same
// 128 q rows. K/V staged by global_load_lds with pre-swizzled sources.
// psum on the MFMA pipe (ones-A). setprio(1) around COMPUTE.
// ---------------------------------------------------------------------------
__global__ __launch_bounds__(512, 4) void attn_kernel(
    const bf16_t* __restrict__ Q, const bf16_t* __restrict__ K,
    const bf16_t* __restrict__ Vt, const int* __restrict__ mask,
    bf16_t* __restrict__ ctx)
{
    const int B   = blockIdx.x;            // 0..511
    const int xcd = B & 7;
    const int idx = B >> 3;                // 0..63
    const int bh  = xcd * 4 + (idx & 3);   // 4 heads per XCD -> K/V L2-local
    const int q0  = (idx >> 2) * 128;      // block q base (0..1920)
    const int b   = bh >> 4;
    const int h   = bh & 15;
    const int tid  = threadIdx.x;
    const int wave = tid >> 6;             // 0..7
    const int wq   = wave & 3;             // q sub-block within the half
    const int kh   = wave >> 2;            // kv half
    const int lane = tid & 63;
    const int l16  = lane & 15;
    const int quad = lane >> 4;
    const int r7   = l16 & 7;

    const bf16_t* Qh = Q  + (size_t)bh * SEQ * HD;
    const bf16_t* Kh = K  + (size_t)bh * SEQ * HD;
    const bf16_t* Vh = Vt + (size_t)bh * HD * SEQ;    // [d][s]
    const int*    mk = mask + b * SEQ;

    // per-kh: Kbuf0 8K | Vbuf0 8K | Kbuf1 8K | Vbuf1 8K = 32K; x2 kh = 64K;
    // + bias 8K = 73728 B. Epilogue merge regions reuse [0, 40960).
    __shared__ __align__(16) char smem[73728];
    char*  base  = smem + kh * 32768;
    char*  Kb0   = base;
    char*  Vb0   = base + 8192;
    char*  Kb1   = base + 16384;
    char*  Vb1   = base + 24576;
    float* bias2 = (float*)(smem + 65536);            // [SEQ]

    const int qw  = q0 + wq * 32;
    const int kvb = kh * KVHALF;

    // ---- staging geometry (per wave: 64 lanes cover 8 rows x 8 chunks) ----
    const int srow = wq * 8 + (lane >> 3);            // tile row 0..31 (this lane)
    const int cK   = lane & 7;                        // 16B chunk
    // K source pre-swizzled: chunk cK of dest row r holds global chunk cK^(r&7)
    const bf16_t* srcK = Kh + (size_t)(kvb + srow) * HD + ((cK ^ (srow & 7)) * 8);
    // V source pre-swizzled (even mask): granules {2cK,2cK+1}^(r&14), contiguous
    const bf16_t* srcV = Vh + (size_t)srow * SEQ + kvb + (((2 * cK) ^ (srow & 14)) * 4);
    const int dofs = wq * 1024;                       // per-wave uniform dest offset

    // ---- read geometry ----
    // aK: logical chunk (kc*4+quad) at row l16 -> phys chunk ^ (l16&7)
    const int kb0 = l16 * 128 + (((quad    ) ^ r7) << 4);
    const int kb1 = l16 * 128 + (((4 + quad) ^ r7) << 4);

    // prologue: stage tile 0, fill bias
    glds16(srcK,                Kb0 + dofs);
    glds16(srcK + 32 * HD,      Kb0 + dofs + 4096);
    glds16(srcV,                Vb0 + dofs);
    glds16(srcV + 32 * SEQ,     Vb0 + dofs + 4096);
    for (int i = tid; i < SEQ; i += 512)
        bias2[i] = (mk[i] ? 0.0f : -1.0e30f) - SHIFT2;

    bf16x8 bQ[2][2];
#pragma unroll
    for (int qh = 0; qh < 2; qh++)
#pragma unroll
        for (int kc = 0; kc < 2; kc++)
            bQ[qh][kc] = ldg8(Qh + (size_t)(qw + qh * 16 + l16) * HD + kc * 32 + quad * 8);

    const bf16x4 onesA = {(bf16_t)1.0f, (bf16_t)1.0f, (bf16_t)1.0f, (bf16_t)1.0f};
    floatx4 O[2][4];
    floatx4 psA[2];
#pragma unroll
    for (int qh = 0; qh < 2; qh++) {
        psA[qh] = (floatx4)0.0f;
#pragma unroll
        for (int dt = 0; dt < 4; dt++) O[qh][dt] = (floatx4)0.0f;
    }

    __syncthreads();                       // tile 0 + bias visible

#define STAGE(kt, KB, VB)                                            \
    do {                                                             \
        const bf16_t* sk_ = srcK + (size_t)(kt) * HD;                \
        const bf16_t* sv_ = srcV + (kt);                             \
        glds16(sk_,            (KB) + dofs);                         \
        glds16(sk_ + 32 * HD,  (KB) + dofs + 4096);                  \
        glds16(sv_,            (VB) + dofs);                         \
        glds16(sv_ + 32 * SEQ, (VB) + dofs + 4096);                  \
    } while (0)

#define COMPUTE(kt, KB, VB)                                                       \
    do {                                                                          \
        __builtin_amdgcn_s_setprio(1);                                            \
        _Pragma("unroll")                                                         \
        for (int kvt = 0; kvt < 4; kvt++) {                                       \
            bf16x8 aK0 = *(const bf16x8*)((KB) + kb0 + kvt * 2048);               \
            bf16x8 aK1 = *(const bf16x8*)((KB) + kb1 + kvt * 2048);               \
            const floatx4 ad = *(const floatx4*)&bias2[kvb + (kt) + kvt * 16 + quad * 4]; \
            bf16x4 pb[2];                                                         \
            _Pragma("unroll")                                                     \
            for (int qh = 0; qh < 2; qh++) {                                      \
                floatx4 s = (floatx4)0.0f;                                        \
                s = mfma16(aK0, bQ[qh][0], s);                                    \
                s = mfma16(aK1, bQ[qh][1], s);                                    \
                floatx4 p;                                                        \
                _Pragma("unroll")                                                 \
                for (int r = 0; r < 4; r++)                                       \
                    p[r] = __builtin_amdgcn_exp2f(fmaf(s[r], L2E, ad[r]));        \
                _Pragma("unroll")                                                 \
                for (int r = 0; r < 4; r++) pb[qh][r] = (bf16_t)p[r];             \
            }                                                                     \
            psA[0] = mfma16k16(onesA, pb[0], psA[0]);                             \
            psA[1] = mfma16k16(onesA, pb[1], psA[1]);                             \
            const int vofs = l16 * 128 + ((((kvt << 2) + quad) ^ (l16 & 14)) << 3); \
            _Pragma("unroll")                                                     \
            for (int dt = 0; dt < 4; dt++) {                                      \
                bf16x4 aV = *(const bf16x4*)((VB) + vofs + dt * 2048);            \
                O[0][dt] = mfma16k16(aV, pb[0], O[0][dt]);                        \
                O[1][dt] = mfma16k16(aV, pb[1], O[1][dt]);                        \
            }                                                                     \
        }                                                                         \
        __builtin_amdgcn_s_setprio(0);                                            \
    } while (0)

    for (int t = 0; t < 16; t += 2) {
        STAGE((t + 1) * 64, Kb1, Vb1);     // issue next-tile DMA (odd buf)
        COMPUTE(t * 64, Kb0, Vb0);
        __syncthreads();                   // drains vmcnt -> buf1 ready
        if (t + 2 < 16) STAGE((t + 2) * 64, Kb0, Vb0);
        COMPUTE((t + 1) * 64, Kb1, Vb1);
        __syncthreads();                   // buf0 ready
    }
#undef STAGE
#undef COMPUTE

    // upper half dumps its partials (40 floats/lane) into wq's merge region
    if (kh == 1) {
        float* mw = (float*)(smem + wq * 10240) + lane * 40;
#pragma unroll
        for (int qh = 0; qh < 2; qh++) {
#pragma unroll
            for (int dt = 0; dt < 4; dt++)
                *(floatx4*)(mw + qh * 16 + dt * 4) = O[qh][dt];
            *(floatx4*)(mw + 32 + qh * 4) = psA[qh];
        }
    }
    __syncthreads();                       // merge data visible
    if (kh == 1) return;

    // lower half: add partner partials (additive: same static shift)
    {
        const float* mr = (const float*)(smem + wq * 10240) + lane * 40;
#pragma unroll
        for (int qh = 0; qh < 2; qh++) {
#pragma unroll
            for (int dt = 0; dt < 4; dt++)
                O[qh][dt] += *(const floatx4*)(mr + qh * 16 + dt * 4);
            psA[qh] += *(const floatx4*)(mr + 32 + qh * 4);
        }
    }

#pragma unroll
    for (int qh = 0; qh < 2; qh++) {
        const float su = psA[qh][0];       // row-sum broadcast by ones-MFMA
        const float linv = (su > 0.0f) ? 1.0f / su : 0.0f;

        // per-wq private scratch inside this wq's (already consumed) region
        bf16_t* Pw = (bf16_t*)(smem + wq * 10240 + qh * 2304);  // 16x72
#pragma unroll
        for (int dt = 0; dt < 4; dt++) {
            floatx4 o = O[qh][dt] * linv;
            bf16x4 pk;
#pragma unroll
            for (int r = 0; r < 4; r++) pk[r] = (bf16_t)o[r];
            *(bf16x4*)&Pw[l16 * 72 + dt * 16 + quad * 4] = pk;
        }
#pragma unroll
        for (int ch = 0; ch < 2; ch++) {
            const int cc  = ch * 64 + lane;
            const int row = cc >> 3;
            const int col = (cc & 7) * 8;
            bf16x8 vv = *(const bf16x8*)&Pw[row * 72 + col];
            *(bf16x8*)&ctx[((size_t)(b * SEQ + qw + qh * 16 + row)) * HID + h * 64 + col] = vv;
        }
    }
}

// ---------------------------------------------------------------------------
// Kernel 3: res = ctx @ Wo^T + bo + X (residual fused). R16 form (2-barrier).
// 64x128 tile, 512 blocks.
// ---------------------------------------------------------------------------
__global__ __launch_bounds__(256) void oproj_kernel(
    const bf16_t* __restrict__ C, const bf16_t* __restrict__ Wo,
    const float* __restrict__ bo, const float* __restrict__ X,
    float* __restrict__ res)
{
    const int tid  = threadIdx.x;
    const int lane = tid & 63;
    const int wave = tid >> 6;
    const int l16  = lane & 15;
    const int quad = lane >> 4;
    const int m_blk = blockIdx.y * 64;
    const int n_blk = blockIdx.x * 128;
    const int n_w   = wave * 32;

    // union: staging (A 4096 + B 8192 B) / fp32 transpose (4 x 2304 B)
    __shared__ __align__(16) char smem[12288];
    bf16_t* As = (bf16_t*)smem;
    bf16_t* Bs = (bf16_t*)(smem + 4096);

    floatx4 acc[4][2];
#pragma unroll
    for (int i = 0; i < 4; i++)
#pragma unroll
        for (int j = 0; j < 2; j++) acc[i][j] = (floatx4)0.0f;

    for (int k0 = 0; k0 < HID; k0 += 32) {
        __syncthreads();
        stage64x32 (C  + (size_t)m_blk * HID, HID, k0, As, wave, lane);
        stage128x32(Wo + (size_t)n_blk * HID, HID, k0, Bs, wave, lane);
        __syncthreads();

        bf16x8 a[4], b[2];
#pragma unroll
        for (int i = 0; i < 4; i++) a[i] = *(const bf16x8*)&As[(i * 16 + l16) * 32 + quad * 8];
#pragma unroll
        for (int j = 0; j < 2; j++) b[j] = *(const bf16x8*)&Bs[(n_w + j * 16 + l16) * 32 + quad * 8];
#pragma unroll
        for (int i = 0; i < 4; i++)
#pragma unroll
            for (int j = 0; j < 2; j++) acc[i][j] = mfma16(a[i], b[j], acc[i][j]);
    }
    __syncthreads();                                       // smem reusable

    float bv_[2];
#pragma unroll
    for (int j = 0; j < 2; j++) bv_[j] = bo[n_blk + n_w + j * 16 + l16];

    float* Tw = (float*)(smem + wave * 2304);              // 16 x 36 fp32
#pragma unroll
    for (int ch = 0; ch < 4; ch++) {
#pragma unroll
        for (int j = 0; j < 2; j++)
#pragma unroll
            for (int r = 0; r < 4; r++)
                Tw[(quad * 4 + r) * 36 + j * 16 + l16] = acc[ch][j][r] + bv_[j];
#pragma unroll
        for (int cc = 0; cc < 2; cc++) {
            const int idx = cc * 64 + lane;                // 0..127
            const int row = idx >> 3;                      // 0..15
            const int col = (idx & 7) * 4;                 // 0..28
            float4 v = *(const float4*)&Tw[row * 36 + col];
            const int m = m_blk + ch * 16 + row;
            const float4 xv = *(const float4*)&X[(size_t)m * HID + n_blk + n_w + col];
            v.x += xv.x; v.y += xv.y; v.z += xv.z; v.w += xv.w;
            *(float4*)&res[(size_t)m * HID + n_blk + n_w + col] = v;
        }
    }
}

// ---------------------------------------------------------------------------
// Kernel 4: LayerNorm(resX) over rows of 1024 -> fp32 out (X already folded in)
// ---------------------------------------------------------------------------
__global__ __launch_bounds__(256) void ln_kernel(
    const float* __restrict__ res,
    const float* __restrict__ g, const float* __restrict__ be,
    float* __restrict__ out)
{
    __shared__ float red1[4], red2[4];
    const int row  = blockIdx.x;
    const int lane = threadIdx.x & 63;
    const int wave = threadIdx.x >> 6;
    const float4 v = ((const float4*)(res + (size_t)row * HID))[threadIdx.x];

    float s = v.x + v.y + v.z + v.w;
#pragma unroll
    for (int off = 1; off < 64; off <<= 1) s += __shfl_xor(s, off, 64);
    if (lane == 0) red1[wave] = s;
    __syncthreads();
    const float mu = (red1[0] + red1[1] + red1[2] + red1[3]) * (1.0f / HID);

    const float d0 = v.x - mu, d1 = v.y - mu, d2 = v.z - mu, d3 = v.w - mu;
    float ss = d0 * d0 + d1 * d1 + d2 * d2 + d3 * d3;
#pragma unroll
    for (int off = 1; off < 64; off <<= 1) ss += __shfl_xor(ss, off, 64);
    if (lane == 0) red2[wave] = ss;
    __syncthreads();
    const float var = (red2[0] + red2[1] + red2[2] + red2[3]) * (1.0f / HID);
    const float rstd = rsqrtf(var + LNEPS);

    const float4 gv = ((const float4*)g)[threadIdx.x];
    const float4 bv = ((const float4*)be)[threadIdx.x];
    float4 o;
    o.x = d0 * rstd * gv.x + bv.x;
    o.y = d1 * rstd * gv.y + bv.y;
    o.z = d2 * rstd * gv.z + bv.z;
    o.w = d3 * rstd * gv.w + bv.w;
    ((float4*)(out + (size_t)row * HID))[threadIdx.x] = o;
}

// ---------------------------------------------------------------------------
extern "C" void kernel_launch(void* const* d_in, const int* in_sizes, int n_in,
                              void* d_out, int out_size, void* d_ws, size_t ws_size,
                              hipStream_t stream)
{
    const float* X  = (const float*)d_in[0];
    const int* mask = (const int*)d_in[1];
    const float* Wq = (const float*)d_in[2];  const float* bq = (const float*)d_in[3];
    const float* Wk = (const float*)d_in[4];  const float* bk = (const float*)d_in[5];
    const float* Wv = (const float*)d_in[6];  const float* bv = (const float*)d_in[7];
    const float* Wo = (const float*)d_in[8];  const float* bo = (const float*)d_in[9];
    const float* g  = (const float*)d_in[10]; const float* be = (const float*)d_in[11];
    float* out = (float*)d_out;

    char* ws = (char*)d_ws;
    bf16_t* Qb  = (bf16_t*)(ws);                          // [0, 8M)
    bf16_t* Kb  = (bf16_t*)(ws + (8ull  << 20));          // [8M, 16M)
    bf16_t* Vb  = (bf16_t*)(ws + (16ull << 20));          // [16M, 24M)  V^T [bh][d][s]
    bf16_t* Cb  = (bf16_t*)(ws + (24ull << 20));          // [24M, 32M)
    float*  Rb  = (float*)(ws);                           // [0, 16M) aliases dead Q/K
    bf16_t* Xc  = (bf16_t*)(ws + (32ull << 20));          // [32M, 40M)
    bf16_t* Wqc = (bf16_t*)(ws + (40ull << 20));
    bf16_t* Wkc = (bf16_t*)(ws + (42ull << 20));
    bf16_t* Wvc = (bf16_t*)(ws + (44ull << 20));
    bf16_t* Woc = (bf16_t*)(ws + (46ull << 20));

    cvt_kernel <<<dim3(512, 1, 5), 256, 0, stream>>>(X, Wq, Wk, Wv, Wo, Xc, Wqc, Wkc, Wvc, Woc);
    qkv_kernel <<<dim3(8, 32, 3), 256, 0, stream>>>(Xc, Wqc, bq, Wkc, bk, Wvc, bv, Qb, Kb, Vb);
    attn_kernel<<<dim3(512), 512, 0, stream>>>(Qb, Kb, Vb, mask, Cb);
    oproj_kernel<<<dim3(8, 64), 256, 0, stream>>>(Cb, Woc, bo, X, Rb);
    ln_kernel  <<<MTOT, 256, 0, stream>>>(Rb, g, be, out);
}